// Round 5
// baseline (133.510 us; speedup 1.0000x reference)
//
#include <hip/hip_runtime.h>
#include <math.h>

#define Bn 8
#define Hn 256
#define Wn 256
#define HW (Hn * Wn)
#define R 4          // output rows per block
#define XR 8         // staged rows per plane (R + 4 halo)
#define RP 264       // padded row length (words); data at [4..259]
#define PSZ (XR * RP)        // 2112 words per plane
// plane p base: p*2112 + (p?16:0)  -> check-plane deltas == 16 (mod 32)
#define ZWOFF 14800  // zero region (64 words) for dead gather slots
#define CBOFF 14864  // combined buffer: 6 rows x RP
#define WQOFF 16448  // A-frag staging: 4*64 uint4 = 1024 words
#define STOT  17472  // 69.9 KB -> 2 blocks/CU

typedef __attribute__((ext_vector_type(8))) short bf16x8;
typedef __attribute__((ext_vector_type(4))) float f32x4;
typedef __attribute__((ext_vector_type(2))) float f32x2;

__device__ __forceinline__ unsigned int pk_bits(unsigned int lo,
                                                unsigned int hi) {
  return __builtin_amdgcn_perm(hi, lo, 0x07060302u);
}
__device__ __forceinline__ unsigned int pk_bf16(float lo, float hi) {
  return pk_bits(__float_as_uint(lo), __float_as_uint(hi));
}

// k-slot -> tap mapping (tap = pl*9 + rr*3 + dx). Bank-pairing: on every
// gather instr q0/q1 lanes hit disjoint 16-bank halves:
//   (pl,rr=0)<->(pl,rr=2): delta 2*RP = 528 == 16 (mod 32)
//   (pl0,rr=1)<->(pl1,rr=1): delta = plane offset = (1+n)*2112+16 == 16 (mod 32)
__device__ __constant__ const int T0c[8] = {0, 1, 2, 9, 10, 11, 3, 4};
__device__ __constant__ const int T1c[8] = {6, 7, 8, 15, 16, 17, 12, 13};
__device__ __constant__ const int T2c[8] = {5, 14, -1, -1, -1, -1, -1, -1};

// R14: FUSED kernel. R10-R13 evidence: sim pinned at 44us across VALU/ILP/
// pipeline/occupancy changes; counters cohere only at ~0.5GHz effective
// clock (DVFS shadow of the harness's 256MB poison fill at 6.1TB/s that
// precedes every iteration). Timed window = fill(44) + sim(44) + mix(28).
// => minimize kernel count + total cycles + HBM: one kernel does
// conv1+ReLU+conv2+sigmoid+gate (MFMA path, 6 branches, +2 halo rows) AND
// the 7->7 3x3 mix conv, all through LDS. comb workspace eliminated.
__global__ __launch_bounds__(256, 2) void fused_kernel(
    const float* __restrict__ x,   // (8,7,256,256)
    const float* __restrict__ W1,  // (6,64,2,3,3)
    const float* __restrict__ b1,  // (6,64)
    const float* __restrict__ W2,  // (6,1,64,1,1)
    const float* __restrict__ b2,  // (6,1)
    const float* __restrict__ Wm,  // (7,7,3,3)
    const float* __restrict__ bm,  // (7,)
    float* __restrict__ out)       // (8,7,256,256)
{
  __shared__ float S[STOT];

  int bi = blockIdx.x;         // 0..511
  int b  = bi >> 6;
  int h0 = (bi & 63) << 2;     // chunk start row
  int t  = threadIdx.x;

  const unsigned int* rowsU = (const unsigned int*)S;
  uint4* wq = (uint4*)&S[WQOFF];

  // ---- stage x: 7 planes x 8 rows (input rows h0-2 .. h0+5) ----
  for (int u = t; u < 56 * 64; u += 256) {
    int rf = u >> 6;           // 0..55
    int p  = rf >> 3, j = rf & 7;
    int col = (u & 63) << 2;
    int po = p * PSZ + (p ? 16 : 0);
    int sp = (p == 0) ? 3 : ((p <= 3) ? p - 1 : p);  // src plane in x
    int hh = h0 - 2 + j;
    float4 v = make_float4(0.f, 0.f, 0.f, 0.f);
    if ((unsigned)hh < (unsigned)Hn)
      v = *(const float4*)(x + ((size_t)b * 7 + sp) * HW + hh * Wn + col);
    *(float4*)&S[po + j * RP + 4 + col] = v;
  }
  if (t < 56) {  // col-edge zeros for all staged frames
    int p = t >> 3, j = t & 7;
    int po = p * PSZ + (p ? 16 : 0);
    S[po + j * RP + 3] = 0.f;
    S[po + j * RP + 260] = 0.f;
  }
  if (t < 6) {   // col-edge zeros for combined buffer (never overwritten)
    S[CBOFF + t * RP + 3] = 0.f;
    S[CBOFF + t * RP + 260] = 0.f;
  }
  if (t >= 192) S[ZWOFF + (t - 192)] = 0.f;  // zero region (64 words)

  // ---- per-lane invariants ----
  int lane = t & 63, wvid = t >> 6;
  int q = lane >> 4, m_ = lane & 15;
  int pxs = wvid * 64 + lane;          // gate-phase pixel
  int bpaddr = ((lane ^ 32) << 2);     // ds_bpermute addr for xor32 reduce

  // gather tap decomposition (branch-independent part)
  unsigned int rowterm[8], plbits = 0;
#pragma unroll
  for (int jh = 0; jh < 8; ++jh) {
    int tap = (q == 0) ? T0c[jh] : (q == 1) ? T1c[jh]
              : (q == 2) ? T2c[jh] : -1;
    if (tap >= 0) {
      int pl = tap / 9, rem = tap - pl * 9;
      int rr = rem / 3, dx = rem - rr * 3;
      if (pl) plbits |= 1u << jh;
      rowterm[jh] = rr * RP + 3 + dx + wvid * 64 + m_;
    } else {
      rowterm[jh] = 0u;
    }
  }
  unsigned int stepA = (q <= 2) ? (unsigned)RP : 0u;  // jh<2 live iff q<=2
  unsigned int stepB = (q < 2) ? (unsigned)RP : 0u;   // jh>=2 live iff q<2

  // mix-phase mapping: thread -> rows {r0, r0+2}, 2 px
  int r0  = t >> 7;            // 0..1
  int pxm = (t & 127) << 1;    // 0..254

  float acc[7][2][2];
#pragma unroll
  for (int oc = 0; oc < 7; ++oc) {
    float bv = bm[oc];
    acc[oc][0][0] = bv; acc[oc][0][1] = bv;
    acc[oc][1][0] = bv; acc[oc][1][1] = bv;
  }

  __syncthreads();  // BAR_0: staged x ready

  // ---- base plane (ic=3) mix contribution, straight from staged x ----
  {
    float v[5][4];
#pragma unroll
    for (int k2 = 0; k2 < 5; ++k2) {
      const float* rp = &S[(r0 + k2 + 1) * RP + 3 + pxm];  // plane 0, j=r+1+dy
      v[k2][0] = rp[0]; v[k2][1] = rp[1]; v[k2][2] = rp[2]; v[k2][3] = rp[3];
    }
#pragma unroll
    for (int oc = 0; oc < 7; ++oc) {
      const float* wo = Wm + oc * 63 + 3 * 9;
#pragma unroll
      for (int dy = 0; dy < 3; ++dy) {
        float w0 = wo[dy * 3], w1 = wo[dy * 3 + 1], w2 = wo[dy * 3 + 2];
#pragma unroll
        for (int rs = 0; rs < 2; ++rs) {
          float* vv = v[rs * 2 + dy];
          acc[oc][rs][0] = fmaf(w0, vv[0],
                            fmaf(w1, vv[1], fmaf(w2, vv[2], acc[oc][rs][0])));
          acc[oc][rs][1] = fmaf(w0, vv[1],
                            fmaf(w1, vv[2], fmaf(w2, vv[3], acc[oc][rs][1])));
        }
      }
    }
  }

  // ---- branch loop: gates -> combined rows -> mix accumulation ----
#pragma unroll 1
  for (int n = 0; n < 6; ++n) {
    int cc = (n < 3) ? n : n + 1;
    int poff = (1 + n) * PSZ + 16;   // check-plane LDS base

    // stage branch weights in MFMA A-layout (k-remap)
    {
      int f = t >> 6, qq = (t >> 4) & 3, m = t & 15;
      int bsrc = (n < 3) ? 0 : 1;
      const float* wch = W1 + ((size_t)(n * 64 + 16 * f + m)) * 18;
      unsigned int kv[4];
#pragma unroll
      for (int jj = 0; jj < 4; ++jj) {
        int ja = 2 * jj, jb = 2 * jj + 1;
        int ta = (qq == 0) ? T0c[ja] : (qq == 1) ? T1c[ja]
                 : (qq == 2) ? T2c[ja] : -1;
        int tb = (qq == 0) ? T0c[jb] : (qq == 1) ? T1c[jb]
                 : (qq == 2) ? T2c[jb] : -1;
        float va = 0.f, vb = 0.f;
        if (ta >= 0) {
          int pl = ta / 9, rem = ta - pl * 9;
          va = wch[(pl ? 1 - bsrc : bsrc) * 9 + rem];
        }
        if (tb >= 0) {
          int pl = tb / 9, rem = tb - pl * 9;
          vb = wch[(pl ? 1 - bsrc : bsrc) * 9 + rem];
        }
        kv[jj] = pk_bf16(va, vb);
      }
      wq[f * 64 + (qq << 4) + m] = make_uint4(kv[0], kv[1], kv[2], kv[3]);
    }

    // per-lane conv2/bias params for this branch
    f32x2 w2A[4], w2B[4];
    f32x4 b1vv[4];
#pragma unroll
    for (int f = 0; f < 4; ++f) {
      float4 tw = *(const float4*)&W2[n * 64 + 16 * f + 4 * q];
      float4 tb = *(const float4*)&b1[n * 64 + 16 * f + 4 * q];
      w2A[f][0] = tw.x; w2A[f][1] = tw.y;
      w2B[f][0] = tw.z; w2B[f][1] = tw.w;
      b1vv[f][0] = tb.x; b1vv[f][1] = tb.y;
      b1vv[f][2] = tb.z; b1vv[f][3] = tb.w;
    }
    float bb = b2[n];

    // gather addresses for this branch
    unsigned int addr[8];
#pragma unroll
    for (int jh = 0; jh < 8; ++jh) {
      bool live = (jh < 2) ? (q <= 2) : (q < 2);
      addr[jh] = live
          ? rowterm[jh] + (((plbits >> jh) & 1u) ? (unsigned)poff : 0u)
          : (unsigned)ZWOFF;
    }

    __syncthreads();  // BAR_A: wq ready; prev mix-read of cbuf done

    bf16x8 afrag[4];
#pragma unroll
    for (int f = 0; f < 4; ++f) afrag[f] = *(const bf16x8*)&wq[f * 64 + lane];

    auto compute2 = [&](const unsigned int* dbuf, float& gA, float& gB) {
      union { unsigned int u[4]; bf16x8 v; } p0, p1;
#pragma unroll
      for (int jj = 0; jj < 4; ++jj) {
        p0.u[jj] = pk_bits(dbuf[2 * jj], dbuf[2 * jj + 1]);
        p1.u[jj] = pk_bits(dbuf[8 + 2 * jj], dbuf[8 + 2 * jj + 1]);
      }
      f32x4 acc0[4], acc1[4];
#pragma unroll
      for (int f = 0; f < 4; ++f) {
        acc0[f] = __builtin_amdgcn_mfma_f32_16x16x32_bf16(afrag[f], p0.v,
                                                          b1vv[f], 0, 0, 0);
        acc1[f] = __builtin_amdgcn_mfma_f32_16x16x32_bf16(afrag[f], p1.v,
                                                          b1vv[f], 0, 0, 0);
      }
      f32x2 sA0 = {0.f, 0.f}, sB0 = {0.f, 0.f};
      f32x2 sA1 = {0.f, 0.f}, sB1 = {0.f, 0.f};
#pragma unroll
      for (int f = 0; f < 4; ++f) {
        f32x2 a01, a23, c01, c23;
        a01[0] = acc0[f][0]; a01[1] = acc0[f][1];
        a23[0] = acc0[f][2]; a23[1] = acc0[f][3];
        c01[0] = acc1[f][0]; c01[1] = acc1[f][1];
        c23[0] = acc1[f][2]; c23[1] = acc1[f][3];
        a01 = __builtin_elementwise_max(a01, (f32x2)0.f);
        a23 = __builtin_elementwise_max(a23, (f32x2)0.f);
        c01 = __builtin_elementwise_max(c01, (f32x2)0.f);
        c23 = __builtin_elementwise_max(c23, (f32x2)0.f);
        sA0 += w2A[f] * a01;
        sB0 += w2B[f] * a23;
        sA1 += w2A[f] * c01;
        sB1 += w2B[f] * c23;
      }
      float sp0 = (sA0[0] + sB0[0]) + (sA0[1] + sB0[1]);
      float sp1 = (sA1[0] + sB1[0]) + (sA1[1] + sB1[1]);
      sp0 += __int_as_float(
          __builtin_amdgcn_ds_swizzle(__float_as_int(sp0), 0x401F));
      sp1 += __int_as_float(
          __builtin_amdgcn_ds_swizzle(__float_as_int(sp1), 0x401F));
      sp0 += __int_as_float(
          __builtin_amdgcn_ds_bpermute(bpaddr, __float_as_int(sp0)));
      sp1 += __int_as_float(
          __builtin_amdgcn_ds_bpermute(bpaddr, __float_as_int(sp1)));
      sp0 += bb;
      sp1 += bb;
      float e0 = __builtin_amdgcn_exp2f(sp0 * -1.442695041f);
      float e1 = __builtin_amdgcn_exp2f(sp1 * -1.442695041f);
      gA = __builtin_amdgcn_rcpf(1.f + e0);
      gB = __builtin_amdgcn_rcpf(1.f + e1);
    };

    // 6 gate rows: k=0..5 <-> image row h0-1+k; combined -> cbuf row k
#pragma unroll 1
    for (int k = 0; k < 6; ++k) {
      unsigned int bufA[16], bufB[16];
#pragma unroll
      for (int jh = 0; jh < 8; ++jh) {
        bufA[jh]     = rowsU[addr[jh]];
        bufA[jh + 8] = rowsU[addr[jh] + 16];
        bufB[jh]     = rowsU[addr[jh] + 32];
        bufB[jh + 8] = rowsU[addr[jh] + 48];
      }
      float g0, g1, g2, g3;
      compute2(bufA, g0, g1);
      compute2(bufB, g2, g3);

      int hi = lane >> 4;
      float gsel = (hi == 0) ? g0 : (hi == 1) ? g1 : (hi == 2) ? g2 : g3;
      float ccv = S[poff + (k + 1) * RP + 4 + pxs];  // check center value
      S[CBOFF + k * RP + 4 + pxs] = gsel * ccv;

#pragma unroll
      for (int jh = 0; jh < 8; ++jh) addr[jh] += (jh < 2) ? stepA : stepB;
    }

    __syncthreads();  // BAR_C: combined rows complete

    // mix accumulation for this plane (ic = cc)
    {
      float v[5][4];
#pragma unroll
      for (int k2 = 0; k2 < 5; ++k2) {
        const float* rp = &S[CBOFF + (r0 + k2) * RP + 3 + pxm];
        v[k2][0] = rp[0]; v[k2][1] = rp[1]; v[k2][2] = rp[2]; v[k2][3] = rp[3];
      }
#pragma unroll
      for (int oc = 0; oc < 7; ++oc) {
        const float* wo = Wm + oc * 63 + cc * 9;
#pragma unroll
        for (int dy = 0; dy < 3; ++dy) {
          float w0 = wo[dy * 3], w1 = wo[dy * 3 + 1], w2 = wo[dy * 3 + 2];
#pragma unroll
          for (int rs = 0; rs < 2; ++rs) {
            float* vv = v[rs * 2 + dy];
            acc[oc][rs][0] = fmaf(w0, vv[0],
                              fmaf(w1, vv[1], fmaf(w2, vv[2], acc[oc][rs][0])));
            acc[oc][rs][1] = fmaf(w0, vv[1],
                              fmaf(w1, vv[2], fmaf(w2, vv[3], acc[oc][rs][1])));
          }
        }
      }
    }
  }

  // ---- store: 7 oc x rows {r0, r0+2} x 2 px ----
  float* ob = out + (size_t)b * 7 * HW;
#pragma unroll
  for (int oc = 0; oc < 7; ++oc) {
#pragma unroll
    for (int rs = 0; rs < 2; ++rs) {
      int h = h0 + r0 + 2 * rs;
      *(float2*)(ob + (size_t)oc * HW + h * Wn + pxm) =
          make_float2(acc[oc][rs][0], acc[oc][rs][1]);
    }
  }
}

extern "C" void kernel_launch(void* const* d_in, const int* in_sizes, int n_in,
                              void* d_out, int out_size, void* d_ws, size_t ws_size,
                              hipStream_t stream) {
  const float* x  = (const float*)d_in[0];
  const float* W1 = (const float*)d_in[1];
  const float* b1 = (const float*)d_in[2];
  const float* W2 = (const float*)d_in[3];
  const float* b2 = (const float*)d_in[4];
  const float* Wm = (const float*)d_in[5];
  const float* bm = (const float*)d_in[6];
  float* out = (float*)d_out;

  fused_kernel<<<8 * (Hn / R), 256, 0, stream>>>(x, W1, b1, W2, b2, Wm, bm,
                                                 out);
}

// Round 6
// 119.360 us; speedup vs baseline: 1.1185x; 1.1185x over previous
//
#include <hip/hip_runtime.h>
#include <math.h>

#define Bn 8
#define Hn 256
#define Wn 256
#define HW (Hn * Wn)
#define ROWS 4
#define RPL 6   // rows per plane staged: ROWS + 2 halo
#define RP 264  // padded row length (words); data at [4..259], zeros at 3/260
#define ZW (12 * RP)  // zero region: rowsF[ZW .. ZW+63] == 0

typedef __attribute__((ext_vector_type(8))) short bf16x8;
typedef __attribute__((ext_vector_type(4))) float f32x4;
typedef __attribute__((ext_vector_type(2))) float f32x2;

__device__ __forceinline__ unsigned int pk_bits(unsigned int lo,
                                                unsigned int hi) {
  return __builtin_amdgcn_perm(hi, lo, 0x07060302u);
}
__device__ __forceinline__ unsigned int pk_bf16(float lo, float hi) {
  return pk_bits(__float_as_uint(lo), __float_as_uint(hi));
}
// packed fma: c + {s,s}*a  (fp-contract -> v_pk_fma_f32)
__device__ __forceinline__ f32x2 fma2(float s, f32x2 a, f32x2 c) {
  f32x2 sv = {s, s};
  return sv * a + c;
}

// k-slot -> tap mapping (tap = pl*9 + rr*3 + dx), bank-pairing preserved:
//   (pl,rr=0)<->(pl,rr=2): delta 2*RP = 528 == 16 (mod 32)
//   (pl0,rr=1)<->(pl1,rr=1): delta 6*RP = 1584 == 16 (mod 32)
__device__ __constant__ const int T0c[8] = {0, 1, 2, 9, 10, 11, 3, 4};
__device__ __constant__ const int T1c[8] = {6, 7, 8, 15, 16, 17, 12, 13};
__device__ __constant__ const int T2c[8] = {5, 14, -1, -1, -1, -1, -1, -1};

// Kernel A (R15 = R13 sim, proven 44us, + free trims). R14 post-mortem:
// fused(71.5) == sim+mix exactly -> time = total issue cycles / ~0.73GHz
// effective clock, regardless of kernel count/occupancy/schedule. So:
// revert fusion (it added +17us window penalty + 1.5x halo recompute),
// cut instruction count instead.
__global__ __launch_bounds__(256, 4) void sim_kernel(
    const float* __restrict__ x,   // (8,7,256,256)
    const float* __restrict__ W1,  // (6,64,2,3,3)
    const float* __restrict__ b1,  // (6,64)
    const float* __restrict__ W2,  // (6,1,64,1,1)
    const float* __restrict__ b2,  // (6,1)
    float* __restrict__ comb)      // (8,7,256,256)
{
  __shared__ float rowsF[12 * RP + 64];  // 12.9 KB rows + zero region
  __shared__ uint4 wq[4][64];            // 4 KB A-frags

  int bi = blockIdx.x;
  int n  = bi >> 9;            // 0..5  (512 blocks per n)
  int b  = (bi >> 6) & 7;      // 0..7
  int h0 = (bi & 63) * ROWS;   // chunk start row
  int cc = (n < 3) ? n : n + 1;
  int t = threadIdx.x;

  const float* xb     = x + (size_t)b * 7 * HW;
  const float* basep  = xb + 3 * HW;
  const float* checkp = xb + (size_t)cc * HW;

  // ---- stage weights in MFMA A-layout with the k-remap ----
  {
    int f = t >> 6, qq = (t >> 4) & 3, m = t & 15;
    int bsrc = (n < 3) ? 0 : 1;  // weight input-ch that multiplies BASE
    const float* wch = W1 + ((size_t)(n * 64 + 16 * f + m)) * 18;
    unsigned int kv[4];
#pragma unroll
    for (int jj = 0; jj < 4; ++jj) {
      int ja = 2 * jj, jb = 2 * jj + 1;
      int ta = (qq == 0) ? T0c[ja] : (qq == 1) ? T1c[ja]
               : (qq == 2) ? T2c[ja] : -1;
      int tb = (qq == 0) ? T0c[jb] : (qq == 1) ? T1c[jb]
               : (qq == 2) ? T2c[jb] : -1;
      float va = 0.f, vb = 0.f;
      if (ta >= 0) {
        int pl = ta / 9, rem = ta - pl * 9;
        va = wch[(pl ? 1 - bsrc : bsrc) * 9 + rem];
      }
      if (tb >= 0) {
        int pl = tb / 9, rem = tb - pl * 9;
        vb = wch[(pl ? 1 - bsrc : bsrc) * 9 + rem];
      }
      kv[jj] = pk_bf16(va, vb);
    }
    wq[f][(qq << 4) + m] = make_uint4(kv[0], kv[1], kv[2], kv[3]);
  }

  // ---- per-lane conv2/bias params (global loads, no LDS dep) ----
  int lane = t & 63, wvid = t >> 6;
  int q = lane >> 4, m_ = lane & 15;
  f32x2 w2A[4], w2B[4];
  f32x4 b1vv[4];
#pragma unroll
  for (int f = 0; f < 4; ++f) {
    float4 tw = *(const float4*)&W2[n * 64 + 16 * f + 4 * q];
    float4 tb = *(const float4*)&b1[n * 64 + 16 * f + 4 * q];
    w2A[f][0] = tw.x; w2A[f][1] = tw.y;
    w2B[f][0] = tw.z; w2B[f][1] = tw.w;
    b1vv[f][0] = tb.x; b1vv[f][1] = tb.y;
    b1vv[f][2] = tb.z; b1vv[f][3] = tb.w;
  }
  float bbl = b2[n] * -1.442695041f;  // bias pre-folded into exp2 fma

  // ---- stage raw rows: 12 rows x 256 cols -> rowsF[rf*RP + 4 + col] ----
  {
    int col = (t & 63) << 2;
#pragma unroll
    for (int it = 0; it < 3; ++it) {
      int rf = it * 4 + (t >> 6);  // 0..11
      int pl = (rf >= RPL) ? 1 : 0;
      int j  = rf - pl * RPL;
      int hh = h0 - 1 + j;
      const float* src = pl ? checkp : basep;
      float4 val = make_float4(0.f, 0.f, 0.f, 0.f);
      if ((unsigned)hh < (unsigned)Hn)
        val = *(const float4*)(src + hh * Wn + col);
      *(float4*)&rowsF[rf * RP + 4 + col] = val;
    }
    if (t < 12) {  // edge zeros
      rowsF[t * RP + 3] = 0.f;
      rowsF[t * RP + 260] = 0.f;
    }
    if (t >= 192) rowsF[ZW + (t - 192)] = 0.f;  // zero region (64 words)
  }

  // ---- per-lane gather table: slot jh (k = 8q + jh) ----
  const unsigned int* rowsU = (const unsigned int*)rowsF;
  unsigned int addr[8];
#pragma unroll
  for (int jh = 0; jh < 8; ++jh) {
    int tap = (q == 0) ? T0c[jh] : (q == 1) ? T1c[jh]
              : (q == 2) ? T2c[jh] : -1;
    if (tap >= 0) {
      int pl = tap / 9, rem = tap - pl * 9;
      int rr = rem / 3, dx = rem - rr * 3;
      addr[jh] = (pl * RPL + rr) * RP + 3 + dx + wvid * 64 + m_;
    } else {
      addr[jh] = (unsigned)ZW;  // zero region; +16/32/48 also zero
    }
  }
  unsigned int stepA = (q <= 2) ? (unsigned)RP : 0u;
  unsigned int stepB = (q < 2) ? (unsigned)RP : 0u;
  int bpaddr = ((lane ^ 32) << 2);  // ds_bpermute byte address for xor32

  __syncthreads();

  // A fragments (contiguous 16 B per lane, conflict-free)
  bf16x8 afrag[4];
#pragma unroll
  for (int f = 0; f < 4; ++f) afrag[f] = *(const bf16x8*)&wq[f][lane];

  float* combcc = comb + ((size_t)b * 7 + cc) * HW;
  int pxs = wvid * 64 + lane;

  auto compute2 = [&](const unsigned int* dbuf, float& gA, float& gB) {
    union { unsigned int u[4]; bf16x8 v; } p0, p1;
#pragma unroll
    for (int jj = 0; jj < 4; ++jj) {
      p0.u[jj] = pk_bits(dbuf[2 * jj], dbuf[2 * jj + 1]);
      p1.u[jj] = pk_bits(dbuf[8 + 2 * jj], dbuf[8 + 2 * jj + 1]);
    }
    f32x4 acc0[4], acc1[4];
#pragma unroll
    for (int f = 0; f < 4; ++f) {
      acc0[f] = __builtin_amdgcn_mfma_f32_16x16x32_bf16(afrag[f], p0.v,
                                                        b1vv[f], 0, 0, 0);
      acc1[f] = __builtin_amdgcn_mfma_f32_16x16x32_bf16(afrag[f], p1.v,
                                                        b1vv[f], 0, 0, 0);
    }
    f32x2 sA0 = {0.f, 0.f}, sB0 = {0.f, 0.f};
    f32x2 sA1 = {0.f, 0.f}, sB1 = {0.f, 0.f};
#pragma unroll
    for (int f = 0; f < 4; ++f) {
      f32x2 a01, a23, c01, c23;
      a01[0] = acc0[f][0]; a01[1] = acc0[f][1];
      a23[0] = acc0[f][2]; a23[1] = acc0[f][3];
      c01[0] = acc1[f][0]; c01[1] = acc1[f][1];
      c23[0] = acc1[f][2]; c23[1] = acc1[f][3];
      a01 = __builtin_elementwise_max(a01, (f32x2)0.f);
      a23 = __builtin_elementwise_max(a23, (f32x2)0.f);
      c01 = __builtin_elementwise_max(c01, (f32x2)0.f);
      c23 = __builtin_elementwise_max(c23, (f32x2)0.f);
      sA0 += w2A[f] * a01;
      sB0 += w2B[f] * a23;
      sA1 += w2A[f] * c01;
      sB1 += w2B[f] * c23;
    }
    f32x2 s0 = sA0 + sB0, s1 = sA1 + sB1;  // pk add
    float sp0 = s0[0] + s0[1];
    float sp1 = s1[0] + s1[1];
    sp0 += __int_as_float(
        __builtin_amdgcn_ds_swizzle(__float_as_int(sp0), 0x401F));
    sp1 += __int_as_float(
        __builtin_amdgcn_ds_swizzle(__float_as_int(sp1), 0x401F));
    sp0 += __int_as_float(
        __builtin_amdgcn_ds_bpermute(bpaddr, __float_as_int(sp0)));
    sp1 += __int_as_float(
        __builtin_amdgcn_ds_bpermute(bpaddr, __float_as_int(sp1)));
    float e0 = __builtin_amdgcn_exp2f(fmaf(sp0, -1.442695041f, bbl));
    float e1 = __builtin_amdgcn_exp2f(fmaf(sp1, -1.442695041f, bbl));
    gA = __builtin_amdgcn_rcpf(1.f + e0);
    gB = __builtin_amdgcn_rcpf(1.f + e1);
  };

  unsigned int bufA[16], bufB[16];
#pragma unroll
  for (int jh = 0; jh < 8; ++jh) {
    bufA[jh]     = rowsU[addr[jh]];
    bufA[jh + 8] = rowsU[addr[jh] + 16];
  }

#pragma unroll 1
  for (int r = 0; r < ROWS; ++r) {
    float ccv = rowsF[(RPL + r + 1) * RP + 4 + pxs];  // check center (early)

#pragma unroll
    for (int jh = 0; jh < 8; ++jh) {
      bufB[jh]     = rowsU[addr[jh] + 32];
      bufB[jh + 8] = rowsU[addr[jh] + 48];
    }

    float g0, g1, g2, g3;
    compute2(bufA, g0, g1);

    if (r < ROWS - 1) {
#pragma unroll
      for (int jh = 0; jh < 8; ++jh) {
        addr[jh] += (jh < 2) ? stepA : stepB;
        bufA[jh]     = rowsU[addr[jh]];
        bufA[jh + 8] = rowsU[addr[jh] + 16];
      }
    }

    compute2(bufB, g2, g3);

    int hi = lane >> 4;
    float gsel = (hi == 0) ? g0 : (hi == 1) ? g1 : (hi == 2) ? g2 : g3;
    combcc[(h0 + r) * Wn + pxs] = gsel * ccv;
  }
}

// Kernel B (R15): mix conv (7->7, 3x3, SAME), packed-f32 arithmetic.
// R13 mix = 28us, ~8K cycles/SIMD of scalar v_fma (441/px) -> dominant.
// 4 px/thread: five tap-pairs (v0,v1)..(v4,v5) built once per (ic,dy),
// 7-oc loop in v_pk_fma_f32 (2 px/slot) -> VALU issue ~halved. Same fma
// per element, same order -> bitwise identical to R13.
// Block = (b, 8-row chunk): 256 blocks x 512 thr. LDS 7 x 10 x RP = 73.9KB.
__global__ __launch_bounds__(512) void mix_kernel(
    const float* __restrict__ comb,  // (8,7,256,256), plane 3 unused
    const float* __restrict__ x,     // (8,7,256,256), plane 3 = base
    const float* __restrict__ Wm,    // (7,7,3,3)
    const float* __restrict__ bm,    // (7,)
    float* __restrict__ out)         // (8,7,256,256)
{
  __shared__ float mr[70 * RP];  // 73.9 KB

  int bi = blockIdx.x;           // 0..255
  int b  = bi >> 5;
  int h0 = (bi & 31) << 3;
  int t = threadIdx.x;

  // stage: 70 rows (ic*10 + j) x 64 float4; j=0..9 <-> input row h0-1+j
  for (int u = t; u < 70 * 64; u += 512) {
    int rf = u >> 6;             // 0..69
    int col = (u & 63) << 2;
    int ic = rf / 10, j = rf - ic * 10;
    int hh = h0 - 1 + j;
    const float* src = (ic == 3) ? (x + ((size_t)b * 7 + 3) * HW)
                                 : (comb + ((size_t)b * 7 + ic) * HW);
    float4 v = make_float4(0.f, 0.f, 0.f, 0.f);
    if ((unsigned)hh < (unsigned)Hn)
      v = *(const float4*)(src + hh * Wn + col);
    *(float4*)&mr[rf * RP + 4 + col] = v;
  }
  if (t < 70) {
    mr[t * RP + 3] = 0.f;
    mr[t * RP + 260] = 0.f;
  }
  __syncthreads();

  int r   = t >> 6;           // local row 0..7
  int px0 = (t & 63) << 2;    // 0..252
  int h   = h0 + r;

  f32x2 acc[7][2];
#pragma unroll
  for (int oc = 0; oc < 7; ++oc) {
    float bv = bm[oc];
    acc[oc][0] = (f32x2){bv, bv};
    acc[oc][1] = (f32x2){bv, bv};
  }

#pragma unroll 1
  for (int ic = 0; ic < 7; ++ic) {
    // tap pairs per dy: P[dy][k] = (v_k, v_{k+1}), k=0..4, from 6 scalars
    f32x2 P[3][5];
#pragma unroll
    for (int dy = 0; dy < 3; ++dy) {
      const float* rp = &mr[(ic * 10 + r + dy) * RP + 3 + px0];
      float v0 = rp[0], v1 = rp[1], v2 = rp[2];
      float v3 = rp[3], v4 = rp[4], v5 = rp[5];
      P[dy][0] = (f32x2){v0, v1};
      P[dy][1] = (f32x2){v1, v2};
      P[dy][2] = (f32x2){v2, v3};
      P[dy][3] = (f32x2){v3, v4};
      P[dy][4] = (f32x2){v4, v5};
    }
    const float* wp = Wm + ic * 9;
#pragma unroll
    for (int oc = 0; oc < 7; ++oc) {
      const float* wo = wp + oc * 63;
#pragma unroll
      for (int dy = 0; dy < 3; ++dy) {
        float w0 = wo[dy * 3], w1 = wo[dy * 3 + 1], w2 = wo[dy * 3 + 2];
        acc[oc][0] = fma2(w0, P[dy][0],
                      fma2(w1, P[dy][1], fma2(w2, P[dy][2], acc[oc][0])));
        acc[oc][1] = fma2(w0, P[dy][2],
                      fma2(w1, P[dy][3], fma2(w2, P[dy][4], acc[oc][1])));
      }
    }
  }

  float* ob = out + (size_t)b * 7 * HW + h * Wn + px0;
#pragma unroll
  for (int oc = 0; oc < 7; ++oc) {
    float4 o;
    o.x = acc[oc][0][0]; o.y = acc[oc][0][1];
    o.z = acc[oc][1][0]; o.w = acc[oc][1][1];
    *(float4*)(ob + (size_t)oc * HW) = o;
  }
}

extern "C" void kernel_launch(void* const* d_in, const int* in_sizes, int n_in,
                              void* d_out, int out_size, void* d_ws, size_t ws_size,
                              hipStream_t stream) {
  const float* x  = (const float*)d_in[0];
  const float* W1 = (const float*)d_in[1];
  const float* b1 = (const float*)d_in[2];
  const float* W2 = (const float*)d_in[3];
  const float* b2 = (const float*)d_in[4];
  const float* Wm = (const float*)d_in[5];
  const float* bm = (const float*)d_in[6];
  float* out  = (float*)d_out;
  float* comb = (float*)d_ws;  // 8*7*256*256 floats = 14.7 MB

  sim_kernel<<<6 * 8 * (Hn / ROWS), 256, 0, stream>>>(x, W1, b1, W2, b2, comb);
  mix_kernel<<<8 * (Hn / 8), 512, 0, stream>>>(comb, x, Wm, bm, out);
}